// Round 9
// baseline (293.324 us; speedup 1.0000x reference)
//
#include <hip/hip_runtime.h>
#include <math.h>

#define BB 16
#define H 1024
#define W 1024
#define HW (H*W)
#define NTOT (BB*HW)

typedef unsigned long long u64;

// float32 of np.exp(-0.5*(n/1)^2), n=-2..2 (correctly-rounded decimal literals)
__device__ __constant__ float GW[5] = {
    0.13533528323661270f, 0.60653065971263342f, 1.0f,
    0.60653065971263342f, 0.13533528323661270f};

#define CSCALE ((float)(180.0 / 3.1415926))

// =====================================================================
// K1: fused gaussian(h)+gaussian(v)+sobel+mag+bucket + per-block magmax
// (unchanged from round 8)
// =====================================================================
#define TW 128
#define TH 8
__global__ __launch_bounds__(256, 8) void k_smooth_sobel(const float* __restrict__ img,
                                                         float* __restrict__ mag,
                                                         unsigned char* __restrict__ bucket,
                                                         float* __restrict__ partial) {
#pragma clang fp contract(off)
    __shared__ float sA[14 * 136 + 16];
    __shared__ float sB[14 * 132];
    __shared__ float red[256];

    const int tid = threadIdx.x;
    const int x0 = blockIdx.x * TW;
    const int y0 = blockIdx.y * TH;
    const int b = blockIdx.z;
    const size_t base = (size_t)b * HW;

    for (int idx = tid; idx < 14 * 34; idx += 256) {
        int r = idx / 34, v = idx - r * 34;
        int gy = y0 - 3 + r;
        int gxv = x0 - 4 + v * 4;
        float4 val = make_float4(0.f, 0.f, 0.f, 0.f);
        if (gy >= 0 && gy < H && gxv >= 0 && gxv <= W - 4)
            val = *(const float4*)&img[base + (size_t)gy * W + gxv];
        *(float4*)&sA[r * 136 + v * 4] = val;
    }
    __syncthreads();

    for (int idx = tid; idx < 14 * 33; idx += 256) {
        int r = idx / 33, g = idx - r * 33;
        const float* p = &sA[r * 136 + g * 4];
        float4 A0 = *(const float4*)p;
        float4 A1 = *(const float4*)(p + 4);
        float4 A2 = *(const float4*)(p + 8);
        float a_[12] = {A0.x, A0.y, A0.z, A0.w, A1.x, A1.y, A1.z, A1.w,
                        A2.x, A2.y, A2.z, A2.w};
        float o[4];
#pragma unroll
        for (int j = 0; j < 4; ++j) {
            float s = 0.0f;
#pragma unroll
            for (int k = 0; k < 5; ++k) s = s + GW[k] * a_[j + 1 + k];
            o[j] = s;
        }
        *(float4*)&sB[r * 132 + g * 4] = make_float4(o[0], o[1], o[2], o[3]);
    }
    __syncthreads();

    for (int idx = tid; idx < 10 * 33; idx += 256) {
        int rr = idx / 33, g = idx - rr * 33;
        float bb[20];
#pragma unroll
        for (int k = 0; k < 5; ++k) {
            float4 t = *(const float4*)&sB[(rr + k) * 132 + g * 4];
            bb[k * 4 + 0] = t.x; bb[k * 4 + 1] = t.y;
            bb[k * 4 + 2] = t.z; bb[k * 4 + 3] = t.w;
        }
        int gy = y0 - 1 + rr;
        bool rowok = (gy >= 0 && gy < H);
        float o[4];
#pragma unroll
        for (int j = 0; j < 4; ++j) {
            float s = 0.0f;
#pragma unroll
            for (int k = 0; k < 5; ++k) s = s + GW[k] * bb[k * 4 + j];
            int gx = x0 - 1 + g * 4 + j;
            o[j] = (rowok && gx >= 0 && gx < W) ? s : 0.0f;
        }
        *(float4*)&sA[rr * 136 + g * 4] = make_float4(o[0], o[1], o[2], o[3]);
    }
    __syncthreads();

    const int r = tid >> 5;
    const int cg = (tid & 31) * 4;
    const int y = y0 + r;
    const float* P0 = &sA[r * 136 + cg];
    const float* P1 = P0 + 136;
    const float* P2 = P1 + 136;
    float4 q0 = *(const float4*)P0; float2 e0 = *(const float2*)(P0 + 4);
    float4 q1 = *(const float4*)P1; float2 e1 = *(const float2*)(P1 + 4);
    float4 q2 = *(const float4*)P2; float2 e2 = *(const float2*)(P2 + 4);
    float r0[6] = {q0.x, q0.y, q0.z, q0.w, e0.x, e0.y};
    float r1[6] = {q1.x, q1.y, q1.z, q1.w, e1.x, e1.y};
    float r2[6] = {q2.x, q2.y, q2.z, q2.w, e2.x, e2.y};

    float tmax = 0.0f;
    float mg[4];
    unsigned int bk = 0;
#pragma unroll
    for (int j = 0; j < 4; ++j) {
        float a00 = r0[j], a01 = r0[j + 1], a02 = r0[j + 2];
        float a10 = r1[j],                  a12 = r1[j + 2];
        float a20 = r2[j], a21 = r2[j + 1], a22 = r2[j + 2];

        float Ix = a00;
        Ix = Ix - a02;
        Ix = Ix + 2.0f * a10;
        Ix = Ix - 2.0f * a12;
        Ix = Ix + a20;
        Ix = Ix - a22;

        float Iy = a00;
        Iy = Iy + 2.0f * a01;
        Iy = Iy + a02;
        Iy = Iy - a20;
        Iy = Iy - 2.0f * a21;
        Iy = Iy - a22;

        float t1 = Ix * Ix;
        float t2 = Iy * Iy;
        float m = sqrtf(t1 + t2);
        mg[j] = m;
        tmax = fmaxf(tmax, m);

        float ax = fabsf(Ix), ay = fabsf(Iy);
        float mn = fminf(ax, ay), mx = fmaxf(ax, ay);
        float cr = mn * 0.92387953f - mx * 0.38268343f;
        int bidx;
        if (fabsf(cr) < mx * 3e-5f) {
            float fa2 = (float)atan2((double)Iy, (double)Ix);
            float d2 = fa2 * CSCALE;
            d2 = d2 + 180.0f;
            float t2d = d2 / 45.0f;
            float rr2 = rintf(t2d);
            bidx = ((int)rr2) & 7;
        } else if (ay <= ax * 0.41421356f) {
            bidx = signbit(Ix) ? 0 : 4;
        } else if (ay >= ax * 2.41421356f) {
            bidx = (Iy >= 0.0f) ? 6 : 2;
        } else {
            bidx = (Iy >= 0.0f) ? ((Ix >= 0.0f) ? 5 : 7)
                                : ((Ix >= 0.0f) ? 3 : 1);
        }
        bk |= ((unsigned int)bidx) << (8 * j);
    }
    *(float4*)&mag[base + (size_t)y * W + x0 + cg] = make_float4(mg[0], mg[1], mg[2], mg[3]);
    *(unsigned int*)&bucket[base + (size_t)y * W + x0 + cg] = bk;

    red[tid] = tmax;
    __syncthreads();
    for (int s = 128; s > 0; s >>= 1) {
        if (tid < s) red[tid] = fmaxf(red[tid], red[tid + s]);
        __syncthreads();
    }
    if (tid == 0) {
        int pb = (blockIdx.z * 128 + blockIdx.y) * 8 + blockIdx.x;
        partial[pb] = red[0];
    }
}

// ---------------- per-image max over 1024 block partials ----------------
__global__ __launch_bounds__(256) void k_redmax_img(const float* __restrict__ partial,
                                                    float* __restrict__ magmax) {
    __shared__ float red[256];
    const float* p = partial + blockIdx.x * 1024;
    float m = 0.0f;
    for (int k = threadIdx.x; k < 1024; k += 256) m = fmaxf(m, p[k]);
    red[threadIdx.x] = m;
    __syncthreads();
    for (int s = 128; s > 0; s >>= 1) {
        if (threadIdx.x < s) red[threadIdx.x] = fmaxf(red[threadIdx.x], red[threadIdx.x + s]);
        __syncthreads();
    }
    if (threadIdx.x == 0) magmax[blockIdx.x] = red[0];
}

// =====================================================================
// NMS wave-stripe: wave = 64-col stripe, marches 64 rows. Three mag rows
// (+L/R shuffle variants) in registers; neighbor pick via cndmask tree;
// __ballot(is_max) IS the Mb word. Division-free compares as round 7/8.
// =====================================================================
__global__ __launch_bounds__(256, 8) void k_nms_s(const float* __restrict__ mag,
                                                  const unsigned char* __restrict__ bucket,
                                                  const float* __restrict__ magmax,
                                                  u64* __restrict__ Mb,
                                                  float* __restrict__ partial) {
#pragma clang fp contract(off)
    __shared__ float red[256];
    const int tid = threadIdx.x;
    const int L = tid & 63, wv = tid >> 6;
    const int sx = blockIdx.x * 4 + wv;     // stripe index 0..15
    const int x0 = sx * 64;
    const int y0 = blockIdx.y * 64;
    const int b = blockIdx.z;
    const size_t base = (size_t)b * HW;
    const float M = magmax[b];
    const int x = x0 + L;
    const int wbase = (((b << 8) | (blockIdx.y << 4) | sx)) * 64;

    auto loadRow = [&](int y, float& Lv, float& Cv, float& Rv) {
        float c = 0.0f, l = 0.0f, rr = 0.0f;
        if (y >= 0 && y < H) {
            c = mag[base + (size_t)y * W + x];
            l = __shfl_up(c, 1);
            rr = __shfl_down(c, 1);
            if (L == 0)  l = (x0 > 0) ? mag[base + (size_t)y * W + (x0 - 1)] : 0.0f;
            if (L == 63) rr = (x0 + 64 < W) ? mag[base + (size_t)y * W + (x0 + 64)] : 0.0f;
        }
        Lv = l; Cv = c; Rv = rr;
    };

    float pL, pC, pR, cL, cC, cR, nL, nC, nR, fL, fC, fR;
    loadRow(y0 - 1, pL, pC, pR);
    loadRow(y0, cL, cC, cR);
    loadRow(y0 + 1, nL, nC, nR);

    float amax = 0.0f;
    for (int i = 0; i < 64; ++i) {
        int y = y0 + i;
        loadRow(y + 2, fL, fC, fR);               // prefetch 1 row ahead
        int bkt = bucket[base + (size_t)y * W + x];
        int t1 = (bkt + 1) & 7;
        bool dyp = (bkt >= 1 && bkt <= 3);        // dy=+1
        bool dyn = (bkt >= 5);                    // dy=-1
        bool dxp = (t1 <= 2);                     // dx=+1  (bkt 0,1,7)
        bool dxn = (t1 >= 4 && t1 <= 6);          // dx=-1  (bkt 3,4,5)

        // bp = mag(y+dy, x+dx)
        float rLv = dyn ? pL : (dyp ? nL : cL);
        float rCv = dyn ? pC : (dyp ? nC : cC);
        float rRv = dyn ? pR : (dyp ? nR : cR);
        float bp = dxn ? rLv : (dxp ? rRv : rCv);
        // bn = mag(y-dy, x-dx)
        float sLv = dyn ? nL : (dyp ? pL : cL);
        float sCv = dyn ? nC : (dyp ? pC : cC);
        float sRv = dyn ? nR : (dyp ? pR : cR);
        float bn = dxn ? sRv : (dxp ? sLv : sCv);

        float a = cC;
        bool g1 = a > bp, g2 = a > bn;
        bool f1 = a >= bp * 1.0000005f;
        bool f2 = a >= bn * 1.0000005f;
        bool im = g1 && g2;
        bool bad = (g1 && !f1) || (g2 && !f2);
        if (__any(bad)) {
            if (bad) {
                float qa = a / M;
                bool r1 = g1, r2 = g2;
                if (g1 && !f1) r1 = qa > (bp / M);
                if (g2 && !f2) r2 = qa > (bn / M);
                im = r1 && r2;
            }
        }
        if (im) amax = fmaxf(amax, a);
        u64 word = __ballot(im);
        if (L == 0) Mb[wbase + i] = word;

        pL = cL; pC = cC; pR = cR;
        cL = nL; cC = nC; cR = nR;
        nL = fL; nC = fC; nR = fR;
    }

    red[tid] = amax;
    __syncthreads();
    for (int s = 128; s > 0; s >>= 1) {
        if (tid < s) red[tid] = fmaxf(red[tid], red[tid + s]);
        __syncthreads();
    }
    // max(thin) over block = RN(max_surviving_a / M): RN monotone => exact
    if (tid == 0)
        partial[(blockIdx.z * 16 + blockIdx.y) * 4 + blockIdx.x] = red[0] / M;
}

// ---------------- global thin-max + per-image threshold bisection ----------------
__global__ __launch_bounds__(1024) void k_finalize_thr(const float* __restrict__ partial,
                                                       float* __restrict__ hdr,
                                                       float* __restrict__ thr) {
    __shared__ float red[1024];
    float m = (threadIdx.x < 1024) ? partial[threadIdx.x] : 0.0f;
    red[threadIdx.x] = m;
    __syncthreads();
    for (int s = 512; s > 0; s >>= 1) {
        if (threadIdx.x < s) red[threadIdx.x] = fmaxf(red[threadIdx.x], red[threadIdx.x + s]);
        __syncthreads();
    }
    if (threadIdx.x == 0) hdr[16] = red[0];
    if (threadIdx.x < 32) {
        float tm = red[0];
        int t = threadIdx.x;
        float M = hdr[t >> 1];
        float T = (t & 1) ? (tm * 0.15f) : 0.00392f;
        if (0.0f / M >= T) { thr[t] = 0.0f; return; }
        unsigned int lo = 0u, hi = 0x7f800000u;
        while (hi - lo > 1u) {
            unsigned int mid = lo + ((hi - lo) >> 1);
            if (__uint_as_float(mid) / M >= T) hi = mid; else lo = mid;
        }
        thr[t] = __uint_as_float(hi);
    }
}

// =====================================================================
// Threshold wave-stripe: row load + Mb word + 2 compares + 2 ballots.
// =====================================================================
__global__ __launch_bounds__(256, 8) void k_thresh_s(const float* __restrict__ mag,
                                                     const u64* __restrict__ Mb,
                                                     const float* __restrict__ hdr,
                                                     const float* __restrict__ thr,
                                                     u64* __restrict__ Sb,
                                                     u64* __restrict__ Wb) {
    const int tid = threadIdx.x;
    const int L = tid & 63, wv = tid >> 6;
    const int sx = blockIdx.x * 4 + wv;
    const int x0 = sx * 64;
    const int y0 = blockIdx.y * 64;
    const int b = blockIdx.z;
    const size_t base = (size_t)b * HW;
    const float Alo = thr[b * 2], Ahi = thr[b * 2 + 1];
    const bool snm = (hdr[16] * 0.15f <= 0.0f);
    const int wbase = (((b << 8) | (blockIdx.y << 4) | sx)) * 64;

    float a_nxt = mag[base + (size_t)y0 * W + x0 + L];
    u64 mw_nxt = Mb[wbase];
    for (int i = 0; i < 64; ++i) {
        float a = a_nxt;
        u64 mw = mw_nxt;
        if (i < 63) {
            a_nxt = mag[base + (size_t)(y0 + i + 1) * W + x0 + L];
            mw_nxt = Mb[wbase + i + 1];
        }
        bool im = (mw >> L) & 1ull;
        bool strong = snm || (im && (a >= Ahi));
        bool weak = (!strong) && im && (a >= Alo);
        u64 sw = __ballot(strong);
        u64 ww = __ballot(weak);
        if (L == 0) { Sb[wbase + i] = sw; Wb[wbase + i] = ww; }
    }
}

// ---------------- hysteresis: bit-parallel 64x64 tile per wave, tile-major ----------------
template <bool LAST>
__global__ __launch_bounds__(256) void k_hyster_bits(const u64* __restrict__ Wb,
                                                     u64* __restrict__ Sb,
                                                     float* __restrict__ out) {
    const int lane = threadIdx.x & 63;
    const int t = blockIdx.x * 4 + (threadIdx.x >> 6);
    const int ty = (t >> 4) & 15;
    const int tx = t & 15;
    const int idx = t * 64 + lane;

    u64 S = Sb[idx];
    const u64 Wk = Wb[idx];

    u64 hstat = 0;
    if (tx > 0)  hstat |= (Sb[(t - 1) * 64 + lane] >> 63) & 1ull;
    if (tx < 15) hstat |= (Sb[(t + 1) * 64 + lane] & 1ull) << 63;

    u64 halo = 0;
    if (lane == 0 && ty > 0) {
        const int ta = t - 16;
        u64 tc = Sb[ta * 64 + 63];
        u64 hh = (tc << 1) | tc | (tc >> 1);
        if (tx > 0)  hh |= (Sb[(ta - 1) * 64 + 63] >> 63) & 1ull;
        if (tx < 15) hh |= (Sb[(ta + 1) * 64 + 63] & 1ull) << 63;
        halo = hh;
    }
    if (lane == 63 && ty < 15) {
        const int tb = t + 16;
        u64 tc = Sb[tb * 64 + 0];
        u64 hh = (tc << 1) | tc | (tc >> 1);
        if (tx > 0)  hh |= (Sb[(tb - 1) * 64 + 0] >> 63) & 1ull;
        if (tx < 15) hh |= (Sb[(tb + 1) * 64 + 0] & 1ull) << 63;
        halo = hh;
    }

    for (int it = 0; it < 160; ++it) {
        u64 hh = (S << 1) | S | (S >> 1) | hstat;
        u64 up = __shfl_up(hh, 1, 64);
        if (lane == 0) up = halo;
        u64 dn = __shfl_down(hh, 1, 64);
        if (lane == 63) dn = halo;
        u64 dil = hh | up | dn;
        u64 nS = S | (Wk & dil);
        bool ch = (nS != S);
        S = nS;
        if (!__any(ch)) break;
    }

    if (!LAST) {
        Sb[idx] = S;
    } else {
        const int bimg = t >> 8;
        float* op = out + (size_t)bimg * HW + (size_t)(ty * 64) * W + tx * 64 + lane;
#pragma unroll 4
        for (int rr = 0; rr < 64; ++rr) {
            u64 wrow = __shfl(S, rr, 64);
            op[(size_t)rr * W] = ((wrow >> lane) & 1ull) ? 255.0f : 0.0f;
        }
    }
}

extern "C" void kernel_launch(void* const* d_in, const int* in_sizes, int n_in,
                              void* d_out, int out_size, void* d_ws, size_t ws_size,
                              hipStream_t stream) {
    (void)in_sizes; (void)n_in; (void)out_size; (void)ws_size;
    const float* img = (const float*)d_in[0];
    float* out = (float*)d_out;

    // workspace layout
    float* hdr = (float*)d_ws;                 // [0..15]=magmax, [16]=thinmax
    float* thr = hdr + 64;                     // 32 floats: per-image Alo/Ahi
    float* partialA = hdr + 128;               // 16384 floats (K1 blocks)
    float* partialB = partialA + 16384;        // 1024 floats (nms blocks)
    float* A = partialB + 4096;                // mag, 64 MB (16B-aligned)
    unsigned char* C = (unsigned char*)(A + (size_t)NTOT);  // bucket, 16 MB
    u64* Sb = (u64*)(C + (size_t)NTOT);        // strong bits, 2 MB
    u64* Wb = Sb + NTOT / 64;                  // weak bits, 2 MB
    u64* Mb = Wb + NTOT / 64;                  // is_max bits, 2 MB

    dim3 blk(256);
    k_smooth_sobel<<<dim3(8, 128, BB), blk, 0, stream>>>(img, A, C, partialA);
    k_redmax_img<<<dim3(BB), blk, 0, stream>>>(partialA, hdr);
    k_nms_s<<<dim3(4, 16, BB), blk, 0, stream>>>(A, C, hdr, Mb, partialB);
    k_finalize_thr<<<dim3(1), dim3(1024), 0, stream>>>(partialB, hdr, thr);
    k_thresh_s<<<dim3(4, 16, BB), blk, 0, stream>>>(A, Mb, hdr, thr, Sb, Wb);
    for (int p = 0; p < 5; ++p)
        k_hyster_bits<false><<<dim3(NTOT / (64 * 64) / 4), blk, 0, stream>>>(Wb, Sb, out);
    k_hyster_bits<true><<<dim3(NTOT / (64 * 64) / 4), blk, 0, stream>>>(Wb, Sb, out);
}

// Round 10
// 257.406 us; speedup vs baseline: 1.1395x; 1.1395x over previous
//
#include <hip/hip_runtime.h>
#include <math.h>

#define BB 16
#define H 1024
#define W 1024
#define HW (H*W)
#define NTOT (BB*HW)

typedef unsigned long long u64;

// float32 of np.exp(-0.5*(n/1)^2), n=-2..2 (correctly-rounded decimal literals)
__device__ __constant__ float GW[5] = {
    0.13533528323661270f, 0.60653065971263342f, 1.0f,
    0.60653065971263342f, 0.13533528323661270f};

#define CSCALE ((float)(180.0 / 3.1415926))

// =====================================================================
// K1: fused gaussian(h)+gaussian(v)+sobel+mag+bucket + per-block magmax
// (unchanged from round 8)
// =====================================================================
#define TW 128
#define TH 8
__global__ __launch_bounds__(256, 8) void k_smooth_sobel(const float* __restrict__ img,
                                                         float* __restrict__ mag,
                                                         unsigned char* __restrict__ bucket,
                                                         float* __restrict__ partial) {
#pragma clang fp contract(off)
    __shared__ float sA[14 * 136 + 16];
    __shared__ float sB[14 * 132];
    __shared__ float red[256];

    const int tid = threadIdx.x;
    const int x0 = blockIdx.x * TW;
    const int y0 = blockIdx.y * TH;
    const int b = blockIdx.z;
    const size_t base = (size_t)b * HW;

    for (int idx = tid; idx < 14 * 34; idx += 256) {
        int r = idx / 34, v = idx - r * 34;
        int gy = y0 - 3 + r;
        int gxv = x0 - 4 + v * 4;
        float4 val = make_float4(0.f, 0.f, 0.f, 0.f);
        if (gy >= 0 && gy < H && gxv >= 0 && gxv <= W - 4)
            val = *(const float4*)&img[base + (size_t)gy * W + gxv];
        *(float4*)&sA[r * 136 + v * 4] = val;
    }
    __syncthreads();

    for (int idx = tid; idx < 14 * 33; idx += 256) {
        int r = idx / 33, g = idx - r * 33;
        const float* p = &sA[r * 136 + g * 4];
        float4 A0 = *(const float4*)p;
        float4 A1 = *(const float4*)(p + 4);
        float4 A2 = *(const float4*)(p + 8);
        float a_[12] = {A0.x, A0.y, A0.z, A0.w, A1.x, A1.y, A1.z, A1.w,
                        A2.x, A2.y, A2.z, A2.w};
        float o[4];
#pragma unroll
        for (int j = 0; j < 4; ++j) {
            float s = 0.0f;
#pragma unroll
            for (int k = 0; k < 5; ++k) s = s + GW[k] * a_[j + 1 + k];
            o[j] = s;
        }
        *(float4*)&sB[r * 132 + g * 4] = make_float4(o[0], o[1], o[2], o[3]);
    }
    __syncthreads();

    for (int idx = tid; idx < 10 * 33; idx += 256) {
        int rr = idx / 33, g = idx - rr * 33;
        float bb[20];
#pragma unroll
        for (int k = 0; k < 5; ++k) {
            float4 t = *(const float4*)&sB[(rr + k) * 132 + g * 4];
            bb[k * 4 + 0] = t.x; bb[k * 4 + 1] = t.y;
            bb[k * 4 + 2] = t.z; bb[k * 4 + 3] = t.w;
        }
        int gy = y0 - 1 + rr;
        bool rowok = (gy >= 0 && gy < H);
        float o[4];
#pragma unroll
        for (int j = 0; j < 4; ++j) {
            float s = 0.0f;
#pragma unroll
            for (int k = 0; k < 5; ++k) s = s + GW[k] * bb[k * 4 + j];
            int gx = x0 - 1 + g * 4 + j;
            o[j] = (rowok && gx >= 0 && gx < W) ? s : 0.0f;
        }
        *(float4*)&sA[rr * 136 + g * 4] = make_float4(o[0], o[1], o[2], o[3]);
    }
    __syncthreads();

    const int r = tid >> 5;
    const int cg = (tid & 31) * 4;
    const int y = y0 + r;
    const float* P0 = &sA[r * 136 + cg];
    const float* P1 = P0 + 136;
    const float* P2 = P1 + 136;
    float4 q0 = *(const float4*)P0; float2 e0 = *(const float2*)(P0 + 4);
    float4 q1 = *(const float4*)P1; float2 e1 = *(const float2*)(P1 + 4);
    float4 q2 = *(const float4*)P2; float2 e2 = *(const float2*)(P2 + 4);
    float r0[6] = {q0.x, q0.y, q0.z, q0.w, e0.x, e0.y};
    float r1[6] = {q1.x, q1.y, q1.z, q1.w, e1.x, e1.y};
    float r2[6] = {q2.x, q2.y, q2.z, q2.w, e2.x, e2.y};

    float tmax = 0.0f;
    float mg[4];
    unsigned int bk = 0;
#pragma unroll
    for (int j = 0; j < 4; ++j) {
        float a00 = r0[j], a01 = r0[j + 1], a02 = r0[j + 2];
        float a10 = r1[j],                  a12 = r1[j + 2];
        float a20 = r2[j], a21 = r2[j + 1], a22 = r2[j + 2];

        float Ix = a00;
        Ix = Ix - a02;
        Ix = Ix + 2.0f * a10;
        Ix = Ix - 2.0f * a12;
        Ix = Ix + a20;
        Ix = Ix - a22;

        float Iy = a00;
        Iy = Iy + 2.0f * a01;
        Iy = Iy + a02;
        Iy = Iy - a20;
        Iy = Iy - 2.0f * a21;
        Iy = Iy - a22;

        float t1 = Ix * Ix;
        float t2 = Iy * Iy;
        float m = sqrtf(t1 + t2);
        mg[j] = m;
        tmax = fmaxf(tmax, m);

        float ax = fabsf(Ix), ay = fabsf(Iy);
        float mn = fminf(ax, ay), mx = fmaxf(ax, ay);
        float cr = mn * 0.92387953f - mx * 0.38268343f;
        int bidx;
        if (fabsf(cr) < mx * 3e-5f) {
            float fa2 = (float)atan2((double)Iy, (double)Ix);
            float d2 = fa2 * CSCALE;
            d2 = d2 + 180.0f;
            float t2d = d2 / 45.0f;
            float rr2 = rintf(t2d);
            bidx = ((int)rr2) & 7;
        } else if (ay <= ax * 0.41421356f) {
            bidx = signbit(Ix) ? 0 : 4;
        } else if (ay >= ax * 2.41421356f) {
            bidx = (Iy >= 0.0f) ? 6 : 2;
        } else {
            bidx = (Iy >= 0.0f) ? ((Ix >= 0.0f) ? 5 : 7)
                                : ((Ix >= 0.0f) ? 3 : 1);
        }
        bk |= ((unsigned int)bidx) << (8 * j);
    }
    *(float4*)&mag[base + (size_t)y * W + x0 + cg] = make_float4(mg[0], mg[1], mg[2], mg[3]);
    *(unsigned int*)&bucket[base + (size_t)y * W + x0 + cg] = bk;

    red[tid] = tmax;
    __syncthreads();
    for (int s = 128; s > 0; s >>= 1) {
        if (tid < s) red[tid] = fmaxf(red[tid], red[tid + s]);
        __syncthreads();
    }
    if (tid == 0) {
        int pb = (blockIdx.z * 128 + blockIdx.y) * 8 + blockIdx.x;
        partial[pb] = red[0];
    }
}

// ---------------- per-image max over 1024 block partials ----------------
__global__ __launch_bounds__(256) void k_redmax_img(const float* __restrict__ partial,
                                                    float* __restrict__ magmax) {
    __shared__ float red[256];
    const float* p = partial + blockIdx.x * 1024;
    float m = 0.0f;
    for (int k = threadIdx.x; k < 1024; k += 256) m = fmaxf(m, p[k]);
    red[threadIdx.x] = m;
    __syncthreads();
    for (int s = 128; s > 0; s >>= 1) {
        if (threadIdx.x < s) red[threadIdx.x] = fmaxf(red[threadIdx.x], red[threadIdx.x + s]);
        __syncthreads();
    }
    if (threadIdx.x == 0) magmax[blockIdx.x] = red[0];
}

// =====================================================================
// NMS: LDS-tile staging (coalesced float4, latency-hidden) + wave-ballot
// output (no nibble assembly, no in-loop syncs). (dy,dx) arithmetic.
// Division-free compares; rare exact-divide fallback (wave-uniform).
// sN col j <-> x0-4+j ; row r' <-> y0-1+r'.
// =====================================================================
__global__ __launch_bounds__(256, 8) void k_nms_b2(const float* __restrict__ mag,
                                                   const unsigned char* __restrict__ bucket,
                                                   const float* __restrict__ magmax,
                                                   u64* __restrict__ Mb,
                                                   float* __restrict__ partial) {
#pragma clang fp contract(off)
    __shared__ float sN[34 * 136];
    __shared__ float red[256];

    const int tid = threadIdx.x;
    const int x0 = blockIdx.x * 128;
    const int y0 = blockIdx.y * 32;
    const int b = blockIdx.z;
    const size_t base = (size_t)b * HW;
    const float M = magmax[b];

    for (int idx = tid; idx < 34 * 34; idx += 256) {
        int r = idx / 34, v = idx - r * 34;
        int gy = y0 - 1 + r;
        int gxv = x0 - 4 + v * 4;
        float4 val = make_float4(0.f, 0.f, 0.f, 0.f);
        if (gy >= 0 && gy < H && gxv >= 0 && gxv <= W - 4)
            val = *(const float4*)&mag[base + (size_t)gy * W + gxv];
        *(float4*)&sN[r * 136 + v * 4] = val;
    }
    __syncthreads();

    const int L = tid & 63, wv = tid >> 6;
    const int h = wv & 1, wr = wv >> 1;
    const int c = h * 64 + L;              // tile col 0..127
    const int txw = (x0 >> 6) + h;
    float amax = 0.0f;

#pragma unroll 4
    for (int i = 0; i < 16; ++i) {
        const int r = i * 2 + wr;          // 0..31
        const int y = y0 + r;
        int bkt = bucket[base + (size_t)y * W + x0 + c];
        int t1 = (bkt + 1) & 7;
        int dy = ((bkt >= 1 && bkt <= 3) ? 1 : 0) - ((bkt >= 5) ? 1 : 0);
        int dx = ((t1 <= 2) ? 1 : 0) - ((t1 >= 4 && t1 <= 6) ? 1 : 0);

        const int o = (r + 1) * 136 + c + 4;
        const int od = dy * 136 + dx;
        float a  = sN[o];
        float bp = sN[o + od];
        float bn = sN[o - od];

        bool g1 = a > bp, g2 = a > bn;
        bool f1 = a >= bp * 1.0000005f;
        bool f2 = a >= bn * 1.0000005f;
        bool im = g1 && g2;
        bool bad = (g1 && !f1) || (g2 && !f2);
        if (__any(bad)) {
            if (bad) {
                float qa = a / M;
                bool r1 = g1, r2 = g2;
                if (g1 && !f1) r1 = qa > (bp / M);
                if (g2 && !f2) r2 = qa > (bn / M);
                im = r1 && r2;
            }
        }
        if (im) amax = fmaxf(amax, a);
        u64 word = __ballot(im);
        if (L == 0) Mb[((b << 8) | ((y >> 6) << 4) | txw) * 64 + (y & 63)] = word;
    }

    red[tid] = amax;
    __syncthreads();
    for (int s = 128; s > 0; s >>= 1) {
        if (tid < s) red[tid] = fmaxf(red[tid], red[tid + s]);
        __syncthreads();
    }
    // max(thin) over block = RN(max_surviving_a / M): RN monotone => exact
    if (tid == 0)
        partial[(blockIdx.z * 32 + blockIdx.y) * 8 + blockIdx.x] = red[0] / M;
}

// ---------------- global thin-max + per-image threshold bisection ----------------
__global__ __launch_bounds__(1024) void k_finalize_thr(const float* __restrict__ partial,
                                                       float* __restrict__ hdr,
                                                       float* __restrict__ thr) {
    __shared__ float red[1024];
    float m = 0.0f;
    for (int k = threadIdx.x; k < 4096; k += 1024) m = fmaxf(m, partial[k]);
    red[threadIdx.x] = m;
    __syncthreads();
    for (int s = 512; s > 0; s >>= 1) {
        if (threadIdx.x < s) red[threadIdx.x] = fmaxf(red[threadIdx.x], red[threadIdx.x + s]);
        __syncthreads();
    }
    if (threadIdx.x == 0) hdr[16] = red[0];
    if (threadIdx.x < 32) {
        float tm = red[0];
        int t = threadIdx.x;
        float M = hdr[t >> 1];
        float T = (t & 1) ? (tm * 0.15f) : 0.00392f;
        if (0.0f / M >= T) { thr[t] = 0.0f; return; }
        unsigned int lo = 0u, hi = 0x7f800000u;
        while (hi - lo > 1u) {
            unsigned int mid = lo + ((hi - lo) >> 1);
            if (__uint_as_float(mid) / M >= T) hi = mid; else lo = mid;
        }
        thr[t] = __uint_as_float(hi);
    }
}

// =====================================================================
// Threshold: wave-mapped, zero LDS, zero syncs. Coalesced mag rows,
// broadcast Mb word, 2 compares, 2 ballots, lane-0 stores.
// =====================================================================
__global__ __launch_bounds__(256, 8) void k_thresh_w(const float* __restrict__ mag,
                                                     const u64* __restrict__ Mb,
                                                     const float* __restrict__ hdr,
                                                     const float* __restrict__ thr,
                                                     u64* __restrict__ Sb,
                                                     u64* __restrict__ Wb) {
    const int tid = threadIdx.x;
    const int L = tid & 63, wv = tid >> 6;
    const int h = wv & 1, wr = wv >> 1;
    const int x0 = blockIdx.x * 128;
    const int y0 = blockIdx.y * 32;
    const int b = blockIdx.z;
    const size_t base = (size_t)b * HW;
    const float Alo = thr[b * 2], Ahi = thr[b * 2 + 1];
    const bool snm = (hdr[16] * 0.15f <= 0.0f);
    const int txw = (x0 >> 6) + h;

#pragma unroll 4
    for (int i = 0; i < 16; ++i) {
        const int r = i * 2 + wr;
        const int y = y0 + r;
        const int widx = ((b << 8) | ((y >> 6) << 4) | txw) * 64 + (y & 63);
        float a = mag[base + (size_t)y * W + x0 + h * 64 + L];
        u64 mw = Mb[widx];
        bool im = (mw >> L) & 1ull;
        bool strong = snm || (im && (a >= Ahi));
        bool weak = (!strong) && im && (a >= Alo);
        u64 sw = __ballot(strong);
        u64 ww = __ballot(weak);
        if (L == 0) { Sb[widx] = sw; Wb[widx] = ww; }
    }
}

// ---------------- hysteresis: bit-parallel 64x64 tile per wave, tile-major ----------------
template <bool LAST>
__global__ __launch_bounds__(256) void k_hyster_bits(const u64* __restrict__ Wb,
                                                     u64* __restrict__ Sb,
                                                     float* __restrict__ out) {
    const int lane = threadIdx.x & 63;
    const int t = blockIdx.x * 4 + (threadIdx.x >> 6);
    const int ty = (t >> 4) & 15;
    const int tx = t & 15;
    const int idx = t * 64 + lane;

    u64 S = Sb[idx];
    const u64 Wk = Wb[idx];

    u64 hstat = 0;
    if (tx > 0)  hstat |= (Sb[(t - 1) * 64 + lane] >> 63) & 1ull;
    if (tx < 15) hstat |= (Sb[(t + 1) * 64 + lane] & 1ull) << 63;

    u64 halo = 0;
    if (lane == 0 && ty > 0) {
        const int ta = t - 16;
        u64 tc = Sb[ta * 64 + 63];
        u64 hh = (tc << 1) | tc | (tc >> 1);
        if (tx > 0)  hh |= (Sb[(ta - 1) * 64 + 63] >> 63) & 1ull;
        if (tx < 15) hh |= (Sb[(ta + 1) * 64 + 63] & 1ull) << 63;
        halo = hh;
    }
    if (lane == 63 && ty < 15) {
        const int tb = t + 16;
        u64 tc = Sb[tb * 64 + 0];
        u64 hh = (tc << 1) | tc | (tc >> 1);
        if (tx > 0)  hh |= (Sb[(tb - 1) * 64 + 0] >> 63) & 1ull;
        if (tx < 15) hh |= (Sb[(tb + 1) * 64 + 0] & 1ull) << 63;
        halo = hh;
    }

    for (int it = 0; it < 160; ++it) {
        u64 hh = (S << 1) | S | (S >> 1) | hstat;
        u64 up = __shfl_up(hh, 1, 64);
        if (lane == 0) up = halo;
        u64 dn = __shfl_down(hh, 1, 64);
        if (lane == 63) dn = halo;
        u64 dil = hh | up | dn;
        u64 nS = S | (Wk & dil);
        bool ch = (nS != S);
        S = nS;
        if (!__any(ch)) break;
    }

    if (!LAST) {
        Sb[idx] = S;
    } else {
        const int bimg = t >> 8;
        float* op = out + (size_t)bimg * HW + (size_t)(ty * 64) * W + tx * 64 + lane;
#pragma unroll 4
        for (int rr = 0; rr < 64; ++rr) {
            u64 wrow = __shfl(S, rr, 64);
            op[(size_t)rr * W] = ((wrow >> lane) & 1ull) ? 255.0f : 0.0f;
        }
    }
}

extern "C" void kernel_launch(void* const* d_in, const int* in_sizes, int n_in,
                              void* d_out, int out_size, void* d_ws, size_t ws_size,
                              hipStream_t stream) {
    (void)in_sizes; (void)n_in; (void)out_size; (void)ws_size;
    const float* img = (const float*)d_in[0];
    float* out = (float*)d_out;

    // workspace layout
    float* hdr = (float*)d_ws;                 // [0..15]=magmax, [16]=thinmax
    float* thr = hdr + 64;                     // 32 floats: per-image Alo/Ahi
    float* partialA = hdr + 128;               // 16384 floats (K1 blocks)
    float* partialB = partialA + 16384;        // 4096 floats (nms blocks)
    float* A = partialB + 4096;                // mag, 64 MB (16B-aligned)
    unsigned char* C = (unsigned char*)(A + (size_t)NTOT);  // bucket, 16 MB
    u64* Sb = (u64*)(C + (size_t)NTOT);        // strong bits, 2 MB
    u64* Wb = Sb + NTOT / 64;                  // weak bits, 2 MB
    u64* Mb = Wb + NTOT / 64;                  // is_max bits, 2 MB

    dim3 blk(256);
    k_smooth_sobel<<<dim3(8, 128, BB), blk, 0, stream>>>(img, A, C, partialA);
    k_redmax_img<<<dim3(BB), blk, 0, stream>>>(partialA, hdr);
    k_nms_b2<<<dim3(8, 32, BB), blk, 0, stream>>>(A, C, hdr, Mb, partialB);
    k_finalize_thr<<<dim3(1), dim3(1024), 0, stream>>>(partialB, hdr, thr);
    k_thresh_w<<<dim3(8, 32, BB), blk, 0, stream>>>(A, Mb, hdr, thr, Sb, Wb);
    for (int p = 0; p < 5; ++p)
        k_hyster_bits<false><<<dim3(NTOT / (64 * 64) / 4), blk, 0, stream>>>(Wb, Sb, out);
    k_hyster_bits<true><<<dim3(NTOT / (64 * 64) / 4), blk, 0, stream>>>(Wb, Sb, out);
}